// Round 9
// baseline (359.453 us; speedup 1.0000x reference)
//
#include <hip/hip_runtime.h>
#include <hip/hip_bf16.h>
#include <math.h>

// Problem constants (fixed by the reference setup)
constexpr int B = 8;
constexpr int V = 262144;
constexpr int J = 64;
constexpr int K = 4;
constexpr int G = 2048;
constexpr int L = 8;
constexpr int E = 1835008;
constexpr float EPS = 1e-8f;
constexpr int NBLK = V / 256;   // 1024 scan blocks
constexpr int NBKT = 8;         // XCD buckets (vertex-space, VPB = 2^15)
constexpr int VPB = V / NBKT;   // 32768 keys per bucket
constexpr int BKT_GRID = 8192;  // blocks for bucketed kernels
constexpr int PT5 = 1024;       // posed5 block size (1 block/CU, 16 waves)
constexpr int NP1 = 2048;       // partition grid
constexpr int EPB = E / NP1;    // 896 edges per partition block

__device__ inline unsigned bf16bits(float x) {
  unsigned u = __float_as_uint(x);
  return (u + 0x7fffu + ((u >> 16) & 1u)) >> 16;  // round-to-nearest-even
}

// ---------------------------------------------------------------------------
// Kernel 0: per (b,j) normalized joint quat + dual part jd = 0.5*qmul((0,t),q)
// ---------------------------------------------------------------------------
__global__ __launch_bounds__(256) void jqd_kernel(
    const float* __restrict__ jquat, const float* __restrict__ jtrans,
    float* __restrict__ ws) {
  int i = blockIdx.x * blockDim.x + threadIdx.x;
  if (i >= B * J) return;
  float qw = jquat[i * 4 + 0];
  float qx = jquat[i * 4 + 1];
  float qy = jquat[i * 4 + 2];
  float qz = jquat[i * 4 + 3];
  float inv = 1.0f / (sqrtf(qw * qw + qx * qx + qy * qy + qz * qz) + EPS);
  qw *= inv; qx *= inv; qy *= inv; qz *= inv;
  float tx = jtrans[i * 3 + 0];
  float ty = jtrans[i * 3 + 1];
  float tz = jtrans[i * 3 + 2];
  float dw = -0.5f * (tx * qx + ty * qy + tz * qz);
  float dx = 0.5f * (qw * tx + (ty * qz - tz * qy));
  float dy = 0.5f * (qw * ty + (tz * qx - tx * qz));
  float dz = 0.5f * (qw * tz + (tx * qy - ty * qx));
  float* o = ws + (size_t)i * 8;
  o[0] = qw; o[1] = qx; o[2] = qy; o[3] = qz;
  o[4] = dw; o[5] = dx; o[6] = dy; o[7] = dz;
}

// ---------------------------------------------------------------------------
// Kernel 0b: per (b,g) affine transform, packed [G][3]float4 per batch.
// warped = M*p + T, T = gp + nt - M*gp. Row r = float4 {m_r0,m_r1,m_r2,t_r}.
// ---------------------------------------------------------------------------
__global__ __launch_bounds__(256) void nmat_kernel(
    const float* __restrict__ npos, const float* __restrict__ nquat,
    const float* __restrict__ ntrans, float* __restrict__ nmt) {
  int i = blockIdx.x * blockDim.x + threadIdx.x;
  if (i >= B * G) return;
  int g = i & (G - 1);
  float4 q = *reinterpret_cast<const float4*>(nquat + (size_t)i * 4);
  float qw = q.x, qx = q.y, qy = q.z, qz = q.w;
  float inv = 1.0f / (sqrtf(qw * qw + qx * qx + qy * qy + qz * qz) + EPS);
  qw *= inv; qx *= inv; qy *= inv; qz *= inv;
  float xx = qx * qx, yy = qy * qy, zz = qz * qz;
  float xy = qx * qy, xz = qx * qz, yz = qy * qz;
  float wx = qw * qx, wy = qw * qy, wz = qw * qz;
  float m00 = 1.f - 2.f * (yy + zz), m01 = 2.f * (xy - wz), m02 = 2.f * (xz + wy);
  float m10 = 2.f * (xy + wz), m11 = 1.f - 2.f * (xx + zz), m12 = 2.f * (yz - wx);
  float m20 = 2.f * (xz - wy), m21 = 2.f * (yz + wx), m22 = 1.f - 2.f * (xx + yy);
  float gx = npos[g * 3 + 0], gy = npos[g * 3 + 1], gz = npos[g * 3 + 2];
  float tx = ntrans[(size_t)i * 3 + 0] + gx - (m00 * gx + m01 * gy + m02 * gz);
  float ty = ntrans[(size_t)i * 3 + 1] + gy - (m10 * gx + m11 * gy + m12 * gz);
  float tz = ntrans[(size_t)i * 3 + 2] + gz - (m20 * gx + m21 * gy + m22 * gz);
  float4* o = reinterpret_cast<float4*>(nmt + (size_t)i * 12);
  o[0] = make_float4(m00, m01, m02, tx);
  o[1] = make_float4(m10, m11, m12, ty);
  o[2] = make_float4(m20, m21, m22, tz);
}

// ---------------------------------------------------------------------------
// posed5 — LDS-staged node table, ds_read_b128 gathers. 1024 thr, 96 KB LDS.
// mode: 0 = write pvm16, 2 = no pvm16 + zero lap
// ---------------------------------------------------------------------------
__global__ __launch_bounds__(PT5) void posed5_kernel(
    const float* __restrict__ tv, const float* __restrict__ sw_in,
    const float* __restrict__ lw_in, const int* __restrict__ sidx,
    const int* __restrict__ lidx, const float* __restrict__ nmt,
    const float* __restrict__ jqd, float* __restrict__ out,
    unsigned* __restrict__ pvm16, int mode) {
  extern __shared__ float4 sm4[];  // G*3 float4 = 98304 B
  int v = blockIdx.x * PT5 + threadIdx.x;

  float px = tv[(size_t)v * 3 + 0];
  float py = tv[(size_t)v * 3 + 1];
  float pz = tv[(size_t)v * 3 + 2];

  int4 si = *reinterpret_cast<const int4*>(sidx + (size_t)v * 4);
  float4 swv = *reinterpret_cast<const float4*>(sw_in + (size_t)v * 4);
  int4 li0 = *reinterpret_cast<const int4*>(lidx + (size_t)v * 8);
  int4 li1 = *reinterpret_cast<const int4*>(lidx + (size_t)v * 8 + 4);
  float4 lw0 = *reinterpret_cast<const float4*>(lw_in + (size_t)v * 8);
  float4 lw1 = *reinterpret_cast<const float4*>(lw_in + (size_t)v * 8 + 4);

  float sinv = 1.0f / (swv.x + swv.y + swv.z + swv.w + EPS);
  float swn[K] = {swv.x * sinv, swv.y * sinv, swv.z * sinv, swv.w * sinv};
  int sj[K] = {si.x, si.y, si.z, si.w};

  float linv =
      1.0f / (lw0.x + lw0.y + lw0.z + lw0.w + lw1.x + lw1.y + lw1.z + lw1.w + EPS);
  float lwn[L] = {lw0.x * linv, lw0.y * linv, lw0.z * linv, lw0.w * linv,
                  lw1.x * linv, lw1.y * linv, lw1.z * linv, lw1.w * linv};
  int gi[L] = {li0.x * 3, li0.y * 3, li0.z * 3, li0.w * 3,
               li1.x * 3, li1.y * 3, li1.z * 3, li1.w * 3};

  constexpr size_t LAPOFF = (size_t)B * V * 3;
  unsigned pk[2 * B];

  for (int b = 0; b < B; ++b) {
    __syncthreads();
    const float4* src = reinterpret_cast<const float4*>(nmt + (size_t)b * G * 12);
#pragma unroll
    for (int it = 0; it < (G * 3) / PT5; ++it) {
      int q = it * PT5 + threadIdx.x;
      sm4[q] = src[q];
    }
    __syncthreads();

    float ex = 0.f, ey = 0.f, ez = 0.f;
#pragma unroll
    for (int l = 0; l < L; ++l) {
      float4 r0 = sm4[gi[l] + 0];
      float4 r1 = sm4[gi[l] + 1];
      float4 r2 = sm4[gi[l] + 2];
      float w = lwn[l];
      ex += w * (r0.x * px + r0.y * py + r0.z * pz + r0.w);
      ey += w * (r1.x * px + r1.y * py + r1.z * pz + r1.w);
      ez += w * (r2.x * px + r2.y * py + r2.z * pz + r2.w);
    }

    float rbw = 0.f, rbx = 0.f, rby = 0.f, rbz = 0.f;
    float dbw = 0.f, dbx = 0.f, dby = 0.f, dbz = 0.f;
    float r0w = 0.f, r0x = 0.f, r0y = 0.f, r0z = 0.f;
#pragma unroll
    for (int k = 0; k < K; ++k) {
      const float* eptr = jqd + ((size_t)b * J + sj[k]) * 8;
      float4 qf = *reinterpret_cast<const float4*>(eptr);
      float4 df = *reinterpret_cast<const float4*>(eptr + 4);
      float qw = qf.x, qx = qf.y, qy = qf.z, qz = qf.w;
      if (k == 0) { r0w = qw; r0x = qx; r0y = qy; r0z = qz; }
      float dotr = qw * r0w + qx * r0x + qy * r0y + qz * r0z;
      float s = (dotr >= 0.0f) ? swn[k] : -swn[k];
      rbw += s * qw; rbx += s * qx; rby += s * qy; rbz += s * qz;
      dbw += s * df.x; dbx += s * df.y; dby += s * df.z; dbz += s * df.w;
    }
    float ninv = 1.0f / (sqrtf(rbw * rbw + rbx * rbx + rby * rby + rbz * rbz) + EPS);
    rbw *= ninv; rbx *= ninv; rby *= ninv; rbz *= ninv;
    dbw *= ninv; dbx *= ninv; dby *= ninv; dbz *= ninv;

    float txx = 2.0f * (rbw * dbx - dbw * rbx + (rby * dbz - rbz * dby));
    float tyy = 2.0f * (rbw * dby - dbw * rby + (rbz * dbx - rbx * dbz));
    float tzz = 2.0f * (rbw * dbz - dbw * rbz + (rbx * dby - rby * dbx));

    float cx = rby * ez - rbz * ey + rbw * ex;
    float cy = rbz * ex - rbx * ez + rbw * ey;
    float cz = rbx * ey - rby * ex + rbw * ez;
    float ox = ex + 2.0f * (rby * cz - rbz * cy) + txx;
    float oy = ey + 2.0f * (rbz * cx - rbx * cz) + tyy;
    float oz = ez + 2.0f * (rbx * cy - rby * cx) + tzz;

    size_t o = ((size_t)b * V + v) * 3;
    out[o + 0] = ox; out[o + 1] = oy; out[o + 2] = oz;
    pk[b * 2 + 0] = bf16bits(ox) | (bf16bits(oy) << 16);
    pk[b * 2 + 1] = bf16bits(oz);
    if (mode == 2) {
      out[LAPOFF + o + 0] = 0.f;
      out[LAPOFF + o + 1] = 0.f;
      out[LAPOFF + o + 2] = 0.f;
    }
  }

  if (mode == 0) {
    uint4* dst = reinterpret_cast<uint4*>(pvm16 + (size_t)v * 16);
    dst[0] = make_uint4(pk[0], pk[1], pk[2], pk[3]);
    dst[1] = make_uint4(pk[4], pk[5], pk[6], pk[7]);
    dst[2] = make_uint4(pk[8], pk[9], pk[10], pk[11]);
    dst[3] = make_uint4(pk[12], pk[13], pk[14], pk[15]);
  }
}

// ---------------------------------------------------------------------------
// Two-level sort, pass 1: partition edges into 8 vertex-buckets with
// coalesced per-(block,bucket) contiguous writes.
// ---------------------------------------------------------------------------
__global__ __launch_bounds__(256) void p1a_count_kernel(
    const int* __restrict__ st, int* __restrict__ bcnt) {
  __shared__ int lcnt[NBKT];
  int blk = blockIdx.x, t = threadIdx.x;
  if (t < NBKT) lcnt[t] = 0;
  __syncthreads();
  int e0 = blk * EPB;
  for (int idx = e0 + t; idx < e0 + EPB; idx += 256)
    atomicAdd(&lcnt[st[idx] >> 15], 1);
  __syncthreads();
  if (t < NBKT) bcnt[t * NP1 + blk] = lcnt[t];
}

// exclusive scan of bcnt[8*2048] (bucket-major) -> boff2
__global__ __launch_bounds__(1024) void p1b_scan_kernel(
    const int* __restrict__ bcnt, int* __restrict__ boff2) {
  __shared__ int s[1024];
  int t = threadIdx.x;
  int vals[16];
  int sum = 0;
#pragma unroll
  for (int j = 0; j < 16; ++j) { vals[j] = bcnt[t * 16 + j]; sum += vals[j]; }
  s[t] = sum;
  __syncthreads();
  for (int off = 1; off < 1024; off <<= 1) {
    int v = (t >= off) ? s[t - off] : 0;
    __syncthreads();
    s[t] += v;
    __syncthreads();
  }
  int run = s[t] - sum;
#pragma unroll
  for (int j = 0; j < 16; ++j) { boff2[t * 16 + j] = run; run += vals[j]; }
}

__global__ __launch_bounds__(256) void p1c_partition_kernel(
    const int* __restrict__ st, const int* __restrict__ ed,
    const float* __restrict__ w, const int* __restrict__ boff2,
    int* __restrict__ stB, int2* __restrict__ ewB) {
  __shared__ int lbase[NBKT];
  __shared__ int lcur[NBKT];
  int blk = blockIdx.x, t = threadIdx.x;
  if (t < NBKT) { lbase[t] = boff2[t * NP1 + blk]; lcur[t] = 0; }
  __syncthreads();
  int e0 = blk * EPB;
  for (int idx = e0 + t; idx < e0 + EPB; idx += 256) {
    int s = st[idx];
    int b = s >> 15;
    int slot = atomicAdd(&lcur[b], 1);
    int pos = lbase[b] + slot;
    stB[pos] = s;
    ewB[pos] = make_int2(ed[idx], __float_as_int(w[idx]));
  }
}

// ---------------------------------------------------------------------------
// pass 2 (XCD-local, bucket-contiguous reads): vertex hist + CSR scatter
// ---------------------------------------------------------------------------
__global__ __launch_bounds__(256) void hist2_kernel(
    const int* __restrict__ stB, const int* __restrict__ boff2,
    int* __restrict__ cnt) {
  int p = blockIdx.x & (NBKT - 1);
  int beg = boff2[p * NP1];
  int end = (p < NBKT - 1) ? boff2[(p + 1) * NP1] : E;
  int stride = (gridDim.x / NBKT) * 256;
  for (int i = beg + (blockIdx.x / NBKT) * 256 + (int)threadIdx.x; i < end;
       i += stride)
    atomicAdd(&cnt[stB[i]], 1);
}

__global__ __launch_bounds__(256) void scatter2_kernel(
    const int* __restrict__ stB, const int2* __restrict__ ewB,
    const int* __restrict__ boff2, int* __restrict__ cursor,
    int2* __restrict__ e2) {
  int p = blockIdx.x & (NBKT - 1);
  int beg = boff2[p * NP1];
  int end = (p < NBKT - 1) ? boff2[(p + 1) * NP1] : E;
  int stride = (gridDim.x / NBKT) * 256;
  for (int i = beg + (blockIdx.x / NBKT) * 256 + (int)threadIdx.x; i < end;
       i += stride) {
    int pos = atomicAdd(&cursor[stB[i]], 1);
    e2[pos] = ewB[i];
  }
}

// ---------------------------------------------------------------------------
// Vertex CSR scans (cnt -> rowstart, cursor)
// ---------------------------------------------------------------------------
__global__ __launch_bounds__(256) void scan1_kernel(const int* __restrict__ cnt,
                                                    int* __restrict__ excl,
                                                    int* __restrict__ bsum) {
  __shared__ int s[256];
  int t = threadIdx.x;
  int i = blockIdx.x * 256 + t;
  int x = cnt[i];
  s[t] = x;
  __syncthreads();
  for (int off = 1; off < 256; off <<= 1) {
    int val = (t >= off) ? s[t - off] : 0;
    __syncthreads();
    s[t] += val;
    __syncthreads();
  }
  excl[i] = s[t] - x;
  if (t == 255) bsum[blockIdx.x] = s[t];
}

__global__ __launch_bounds__(1024) void scan2_kernel(const int* __restrict__ bsum,
                                                     int* __restrict__ boff) {
  __shared__ int s[NBLK];
  int t = threadIdx.x;
  int x = bsum[t];
  s[t] = x;
  __syncthreads();
  for (int off = 1; off < NBLK; off <<= 1) {
    int val = (t >= off) ? s[t - off] : 0;
    __syncthreads();
    s[t] += val;
    __syncthreads();
  }
  boff[t] = s[t] - x;
}

__global__ __launch_bounds__(256) void scan3_kernel(int* __restrict__ excl,
                                                    const int* __restrict__ boff,
                                                    int* __restrict__ cursor) {
  int i = blockIdx.x * 256 + threadIdx.x;
  int r = excl[i] + boff[blockIdx.x];
  excl[i] = r;
  cursor[i] = r;
  if (i == 0) excl[V] = E;
}

// ---------------------------------------------------------------------------
// Fallback CSR build (old path): XCD-bucketed hist/scatter on original arrays
// ---------------------------------------------------------------------------
__global__ __launch_bounds__(256) void hist_bucketed_kernel(
    const int* __restrict__ st, int* __restrict__ cnt) {
  int p = blockIdx.x & (NBKT - 1);
  int lo = p * VPB, hi = lo + VPB;
  const int4* st4 = reinterpret_cast<const int4*>(st);
  int n4 = E / 4;
  int stride = (gridDim.x / NBKT) * 256;
  for (int i = (blockIdx.x / NBKT) * 256 + (int)threadIdx.x; i < n4; i += stride) {
    int4 s = st4[i];
    if (s.x >= lo && s.x < hi) atomicAdd(&cnt[s.x], 1);
    if (s.y >= lo && s.y < hi) atomicAdd(&cnt[s.y], 1);
    if (s.z >= lo && s.z < hi) atomicAdd(&cnt[s.z], 1);
    if (s.w >= lo && s.w < hi) atomicAdd(&cnt[s.w], 1);
  }
}

__global__ __launch_bounds__(256) void scatter_bucketed_kernel(
    const int* __restrict__ st, const int* __restrict__ ed,
    const float* __restrict__ w, int* __restrict__ cursor,
    int2* __restrict__ e2) {
  int p = blockIdx.x & (NBKT - 1);
  int lo = p * VPB, hi = lo + VPB;
  const int4* st4 = reinterpret_cast<const int4*>(st);
  int n4 = E / 4;
  int stride = (gridDim.x / NBKT) * 256;
  for (int i = (blockIdx.x / NBKT) * 256 + (int)threadIdx.x; i < n4; i += stride) {
    int4 s = st4[i];
    int e = i * 4;
    if (s.x >= lo && s.x < hi) {
      int pos = atomicAdd(&cursor[s.x], 1);
      e2[pos] = make_int2(ed[e + 0], __float_as_int(w[e + 0]));
    }
    if (s.y >= lo && s.y < hi) {
      int pos = atomicAdd(&cursor[s.y], 1);
      e2[pos] = make_int2(ed[e + 1], __float_as_int(w[e + 1]));
    }
    if (s.z >= lo && s.z < hi) {
      int pos = atomicAdd(&cursor[s.z], 1);
      e2[pos] = make_int2(ed[e + 2], __float_as_int(w[e + 2]));
    }
    if (s.w >= lo && s.w < hi) {
      int pos = atomicAdd(&cursor[s.w], 1);
      e2[pos] = make_int2(ed[e + 3], __float_as_int(w[e + 3]));
    }
  }
}

// ---------------------------------------------------------------------------
// Gather from bf16 vertex-major pvm16 ([v][b][2]u32): one 64 B line per edge.
// ---------------------------------------------------------------------------
__global__ __launch_bounds__(256) void lap_gather_pvm16_kernel(
    const int* __restrict__ rowstart, const int2* __restrict__ e2,
    const unsigned* __restrict__ pvm16, float* __restrict__ lap) {
  int v = blockIdx.x * blockDim.x + threadIdx.x;
  if (v >= V) return;
  int beg = rowstart[v];
  int end = rowstart[v + 1];
  float acc[B][3];
#pragma unroll
  for (int b = 0; b < B; ++b) { acc[b][0] = 0.f; acc[b][1] = 0.f; acc[b][2] = 0.f; }
  for (int j = beg; j < end; ++j) {
    int2 ew = e2[j];
    float w = __int_as_float(ew.y);
    const uint4* p = reinterpret_cast<const uint4*>(pvm16 + (size_t)ew.x * 16);
    uint4 q0 = p[0], q1 = p[1], q2 = p[2], q3 = p[3];
    unsigned u[16] = {q0.x, q0.y, q0.z, q0.w, q1.x, q1.y, q1.z, q1.w,
                      q2.x, q2.y, q2.z, q2.w, q3.x, q3.y, q3.z, q3.w};
#pragma unroll
    for (int b = 0; b < B; ++b) {
      acc[b][0] += w * __uint_as_float(u[2 * b] << 16);
      acc[b][1] += w * __uint_as_float(u[2 * b] & 0xffff0000u);
      acc[b][2] += w * __uint_as_float(u[2 * b + 1] << 16);
    }
  }
#pragma unroll
  for (int b = 0; b < B; ++b) {
    size_t o = ((size_t)b * V + v) * 3;
    lap[o + 0] = acc[b][0];
    lap[o + 1] = acc[b][1];
    lap[o + 2] = acc[b][2];
  }
}

// Tier-C fallback: per-edge atomic scatter.
__global__ __launch_bounds__(256) void lap_atomic_kernel(
    const float* __restrict__ lapw, const int* __restrict__ st,
    const int* __restrict__ ed, const float* __restrict__ posed,
    float* __restrict__ lap) {
  int e = blockIdx.x * blockDim.x + threadIdx.x;
  if (e >= E) return;
  float w = lapw[e];
  int s = st[e];
  int d = ed[e];
#pragma unroll
  for (int b = 0; b < B; ++b) {
    size_t pb = ((size_t)b * V + d) * 3;
    size_t ob = ((size_t)b * V + s) * 3;
    atomicAdd(&lap[ob + 0], w * posed[pb + 0]);
    atomicAdd(&lap[ob + 1], w * posed[pb + 1]);
    atomicAdd(&lap[ob + 2], w * posed[pb + 2]);
  }
}

extern "C" void kernel_launch(void* const* d_in, const int* in_sizes, int n_in,
                              void* d_out, int out_size, void* d_ws, size_t ws_size,
                              hipStream_t stream) {
  const float* tv    = (const float*)d_in[0];
  const float* jquat = (const float*)d_in[1];
  const float* jtran = (const float*)d_in[2];
  const float* sw    = (const float*)d_in[3];
  const float* npos  = (const float*)d_in[4];
  const float* nquat = (const float*)d_in[5];
  const float* ntran = (const float*)d_in[6];
  const float* lw    = (const float*)d_in[7];
  const float* lapw  = (const float*)d_in[8];
  const int*   sidx  = (const int*)d_in[9];
  const int*   lidx  = (const int*)d_in[10];
  const int*   lst   = (const int*)d_in[11];
  const int*   led   = (const int*)d_in[12];
  float* out = (float*)d_out;
  float* lap = out + (size_t)B * V * 3;

  // ---- workspace layout ----
  float* jqd      = (float*)d_ws;                       // 16 KB
  float* nmt      = jqd + 4096;                         // 786 KB
  int2*  e2       = (int2*)(nmt + (size_t)B * G * 12);  // E int2 (14.68 MB)
  int*   rowstart = (int*)(e2 + E);                     // V+1
  int*   cnt      = rowstart + (V + 1);                 // V (aliases cursor)
  int*   cursor   = cnt;                                // scan3 fills it
  int*   bsum     = cnt + V;                            // NBLK
  int*   boff     = bsum + NBLK;                        // NBLK
  int*   bcnt     = boff + NBLK;                        // 8*2048
  int*   boff2    = bcnt + NBKT * NP1;                  // 8*2048
  char*  rxRaw    = (char*)(boff2 + NBKT * NP1);
  size_t rxOff    = ((size_t)(rxRaw - (char*)d_ws) + 15) & ~(size_t)15;
  char*  rx       = (char*)d_ws + rxOff;
  int*      stB   = (int*)rx;                           // E ints
  int2*     ewB   = (int2*)(stB + E);                   // E int2
  unsigned* pvm16 = (unsigned*)rx;                      // V*16 u32 (aliases stB/ewB)

  size_t needNew = rxOff + (size_t)E * 4 + (size_t)E * 8;        // ~39.7 MB
  size_t needOld = rxOff + (size_t)V * 16 * sizeof(unsigned);    // ~34.5 MB
  int tier = (ws_size >= needNew) ? 0 : (ws_size >= needOld) ? 1 : 2;

  jqd_kernel<<<(B * J + 255) / 256, 256, 0, stream>>>(jquat, jtran, jqd);
  nmat_kernel<<<(B * G + 255) / 256, 256, 0, stream>>>(npos, nquat, ntran, nmt);

  if (tier == 0) {
    // two-level sort: partition -> XCD-local hist/scatter
    p1a_count_kernel<<<NP1, 256, 0, stream>>>(lst, bcnt);
    p1b_scan_kernel<<<1, 1024, 0, stream>>>(bcnt, boff2);
    p1c_partition_kernel<<<NP1, 256, 0, stream>>>(lst, led, lapw, boff2, stB, ewB);
    hipMemsetAsync(cnt, 0, (size_t)V * sizeof(int), stream);
    hist2_kernel<<<BKT_GRID, 256, 0, stream>>>(stB, boff2, cnt);
    scan1_kernel<<<NBLK, 256, 0, stream>>>(cnt, rowstart, bsum);
    scan2_kernel<<<1, NBLK, 0, stream>>>(bsum, boff);
    scan3_kernel<<<NBLK, 256, 0, stream>>>(rowstart, boff, cursor);
    scatter2_kernel<<<BKT_GRID, 256, 0, stream>>>(stB, ewB, boff2, cursor, e2);
    // posed5 AFTER scatter2: pvm16 aliases stB/ewB (dead now)
    posed5_kernel<<<V / PT5, PT5, G * 3 * sizeof(float4), stream>>>(
        tv, sw, lw, sidx, lidx, nmt, jqd, out, pvm16, 0);
    lap_gather_pvm16_kernel<<<V / 256, 256, 0, stream>>>(rowstart, e2, pvm16, lap);
  } else if (tier == 1) {
    // old path: bucketed hist/scatter on original arrays
    posed5_kernel<<<V / PT5, PT5, G * 3 * sizeof(float4), stream>>>(
        tv, sw, lw, sidx, lidx, nmt, jqd, out, pvm16, 0);
    hipMemsetAsync(cnt, 0, (size_t)V * sizeof(int), stream);
    hist_bucketed_kernel<<<BKT_GRID, 256, 0, stream>>>(lst, cnt);
    scan1_kernel<<<NBLK, 256, 0, stream>>>(cnt, rowstart, bsum);
    scan2_kernel<<<1, NBLK, 0, stream>>>(bsum, boff);
    scan3_kernel<<<NBLK, 256, 0, stream>>>(rowstart, boff, cursor);
    scatter_bucketed_kernel<<<BKT_GRID, 256, 0, stream>>>(lst, led, lapw,
                                                          cursor, e2);
    lap_gather_pvm16_kernel<<<V / 256, 256, 0, stream>>>(rowstart, e2, pvm16, lap);
  } else {
    posed5_kernel<<<V / PT5, PT5, G * 3 * sizeof(float4), stream>>>(
        tv, sw, lw, sidx, lidx, nmt, jqd, out, (unsigned*)jqd /*unused*/, 2);
    lap_atomic_kernel<<<E / 256, 256, 0, stream>>>(lapw, lst, led, out, lap);
  }
}

// Round 10
// 349.608 us; speedup vs baseline: 1.0282x; 1.0282x over previous
//
#include <hip/hip_runtime.h>
#include <hip/hip_bf16.h>
#include <math.h>

// Problem constants (fixed by the reference setup)
constexpr int B = 8;
constexpr int V = 262144;
constexpr int J = 64;
constexpr int K = 4;
constexpr int G = 2048;
constexpr int L = 8;
constexpr int E = 1835008;
constexpr float EPS = 1e-8f;
constexpr int PT5 = 1024;      // posed5 block size (1 block/CU, 16 waves)
constexpr int NB2 = 256;       // fine buckets (1024 vertices each)
constexpr int VB2 = V / NB2;   // 1024
constexpr int PBLK = 256;      // partition blocks
constexpr int EPP = E / PBLK;  // 7168 edges per partition block
constexpr int ASTR = 25;       // LDS acc row stride (gcd(25,32)=1)

__device__ inline unsigned bf16bits(float x) {
  unsigned u = __float_as_uint(x);
  return (u + 0x7fffu + ((u >> 16) & 1u)) >> 16;  // round-to-nearest-even
}

// ---------------------------------------------------------------------------
// Kernel 0: per (b,j) normalized joint quat + dual part jd = 0.5*qmul((0,t),q)
// ---------------------------------------------------------------------------
__global__ __launch_bounds__(256) void jqd_kernel(
    const float* __restrict__ jquat, const float* __restrict__ jtrans,
    float* __restrict__ ws) {
  int i = blockIdx.x * blockDim.x + threadIdx.x;
  if (i >= B * J) return;
  float qw = jquat[i * 4 + 0];
  float qx = jquat[i * 4 + 1];
  float qy = jquat[i * 4 + 2];
  float qz = jquat[i * 4 + 3];
  float inv = 1.0f / (sqrtf(qw * qw + qx * qx + qy * qy + qz * qz) + EPS);
  qw *= inv; qx *= inv; qy *= inv; qz *= inv;
  float tx = jtrans[i * 3 + 0];
  float ty = jtrans[i * 3 + 1];
  float tz = jtrans[i * 3 + 2];
  float dw = -0.5f * (tx * qx + ty * qy + tz * qz);
  float dx = 0.5f * (qw * tx + (ty * qz - tz * qy));
  float dy = 0.5f * (qw * ty + (tz * qx - tx * qz));
  float dz = 0.5f * (qw * tz + (tx * qy - ty * qx));
  float* o = ws + (size_t)i * 8;
  o[0] = qw; o[1] = qx; o[2] = qy; o[3] = qz;
  o[4] = dw; o[5] = dx; o[6] = dy; o[7] = dz;
}

// ---------------------------------------------------------------------------
// Kernel 0b: per (b,g) affine transform, packed [G][3]float4 per batch.
// warped = M*p + T, T = gp + nt - M*gp. Row r = float4 {m_r0,m_r1,m_r2,t_r}.
// ---------------------------------------------------------------------------
__global__ __launch_bounds__(256) void nmat_kernel(
    const float* __restrict__ npos, const float* __restrict__ nquat,
    const float* __restrict__ ntrans, float* __restrict__ nmt) {
  int i = blockIdx.x * blockDim.x + threadIdx.x;
  if (i >= B * G) return;
  int g = i & (G - 1);
  float4 q = *reinterpret_cast<const float4*>(nquat + (size_t)i * 4);
  float qw = q.x, qx = q.y, qy = q.z, qz = q.w;
  float inv = 1.0f / (sqrtf(qw * qw + qx * qx + qy * qy + qz * qz) + EPS);
  qw *= inv; qx *= inv; qy *= inv; qz *= inv;
  float xx = qx * qx, yy = qy * qy, zz = qz * qz;
  float xy = qx * qy, xz = qx * qz, yz = qy * qz;
  float wx = qw * qx, wy = qw * qy, wz = qw * qz;
  float m00 = 1.f - 2.f * (yy + zz), m01 = 2.f * (xy - wz), m02 = 2.f * (xz + wy);
  float m10 = 2.f * (xy + wz), m11 = 1.f - 2.f * (xx + zz), m12 = 2.f * (yz - wx);
  float m20 = 2.f * (xz - wy), m21 = 2.f * (yz + wx), m22 = 1.f - 2.f * (xx + yy);
  float gx = npos[g * 3 + 0], gy = npos[g * 3 + 1], gz = npos[g * 3 + 2];
  float tx = ntrans[(size_t)i * 3 + 0] + gx - (m00 * gx + m01 * gy + m02 * gz);
  float ty = ntrans[(size_t)i * 3 + 1] + gy - (m10 * gx + m11 * gy + m12 * gz);
  float tz = ntrans[(size_t)i * 3 + 2] + gz - (m20 * gx + m21 * gy + m22 * gz);
  float4* o = reinterpret_cast<float4*>(nmt + (size_t)i * 12);
  o[0] = make_float4(m00, m01, m02, tx);
  o[1] = make_float4(m10, m11, m12, ty);
  o[2] = make_float4(m20, m21, m22, tz);
}

// ---------------------------------------------------------------------------
// posed5 — LDS-staged node table, ds_read_b128 gathers. 1024 thr, 96 KB LDS.
// mode: 0 = write pvm16, 2 = no pvm16 + zero lap
// ---------------------------------------------------------------------------
__global__ __launch_bounds__(PT5) void posed5_kernel(
    const float* __restrict__ tv, const float* __restrict__ sw_in,
    const float* __restrict__ lw_in, const int* __restrict__ sidx,
    const int* __restrict__ lidx, const float* __restrict__ nmt,
    const float* __restrict__ jqd, float* __restrict__ out,
    unsigned* __restrict__ pvm16, int mode) {
  extern __shared__ float4 sm4[];  // G*3 float4 = 98304 B
  int v = blockIdx.x * PT5 + threadIdx.x;

  float px = tv[(size_t)v * 3 + 0];
  float py = tv[(size_t)v * 3 + 1];
  float pz = tv[(size_t)v * 3 + 2];

  int4 si = *reinterpret_cast<const int4*>(sidx + (size_t)v * 4);
  float4 swv = *reinterpret_cast<const float4*>(sw_in + (size_t)v * 4);
  int4 li0 = *reinterpret_cast<const int4*>(lidx + (size_t)v * 8);
  int4 li1 = *reinterpret_cast<const int4*>(lidx + (size_t)v * 8 + 4);
  float4 lw0 = *reinterpret_cast<const float4*>(lw_in + (size_t)v * 8);
  float4 lw1 = *reinterpret_cast<const float4*>(lw_in + (size_t)v * 8 + 4);

  float sinv = 1.0f / (swv.x + swv.y + swv.z + swv.w + EPS);
  float swn[K] = {swv.x * sinv, swv.y * sinv, swv.z * sinv, swv.w * sinv};
  int sj[K] = {si.x, si.y, si.z, si.w};

  float linv =
      1.0f / (lw0.x + lw0.y + lw0.z + lw0.w + lw1.x + lw1.y + lw1.z + lw1.w + EPS);
  float lwn[L] = {lw0.x * linv, lw0.y * linv, lw0.z * linv, lw0.w * linv,
                  lw1.x * linv, lw1.y * linv, lw1.z * linv, lw1.w * linv};
  int gi[L] = {li0.x * 3, li0.y * 3, li0.z * 3, li0.w * 3,
               li1.x * 3, li1.y * 3, li1.z * 3, li1.w * 3};

  constexpr size_t LAPOFF = (size_t)B * V * 3;
  unsigned pk[2 * B];

  for (int b = 0; b < B; ++b) {
    __syncthreads();
    const float4* src = reinterpret_cast<const float4*>(nmt + (size_t)b * G * 12);
#pragma unroll
    for (int it = 0; it < (G * 3) / PT5; ++it) {
      int q = it * PT5 + threadIdx.x;
      sm4[q] = src[q];
    }
    __syncthreads();

    float ex = 0.f, ey = 0.f, ez = 0.f;
#pragma unroll
    for (int l = 0; l < L; ++l) {
      float4 r0 = sm4[gi[l] + 0];
      float4 r1 = sm4[gi[l] + 1];
      float4 r2 = sm4[gi[l] + 2];
      float w = lwn[l];
      ex += w * (r0.x * px + r0.y * py + r0.z * pz + r0.w);
      ey += w * (r1.x * px + r1.y * py + r1.z * pz + r1.w);
      ez += w * (r2.x * px + r2.y * py + r2.z * pz + r2.w);
    }

    float rbw = 0.f, rbx = 0.f, rby = 0.f, rbz = 0.f;
    float dbw = 0.f, dbx = 0.f, dby = 0.f, dbz = 0.f;
    float r0w = 0.f, r0x = 0.f, r0y = 0.f, r0z = 0.f;
#pragma unroll
    for (int k = 0; k < K; ++k) {
      const float* eptr = jqd + ((size_t)b * J + sj[k]) * 8;
      float4 qf = *reinterpret_cast<const float4*>(eptr);
      float4 df = *reinterpret_cast<const float4*>(eptr + 4);
      float qw = qf.x, qx = qf.y, qy = qf.z, qz = qf.w;
      if (k == 0) { r0w = qw; r0x = qx; r0y = qy; r0z = qz; }
      float dotr = qw * r0w + qx * r0x + qy * r0y + qz * r0z;
      float s = (dotr >= 0.0f) ? swn[k] : -swn[k];
      rbw += s * qw; rbx += s * qx; rby += s * qy; rbz += s * qz;
      dbw += s * df.x; dbx += s * df.y; dby += s * df.z; dbz += s * df.w;
    }
    float ninv = 1.0f / (sqrtf(rbw * rbw + rbx * rbx + rby * rby + rbz * rbz) + EPS);
    rbw *= ninv; rbx *= ninv; rby *= ninv; rbz *= ninv;
    dbw *= ninv; dbx *= ninv; dby *= ninv; dbz *= ninv;

    float txx = 2.0f * (rbw * dbx - dbw * rbx + (rby * dbz - rbz * dby));
    float tyy = 2.0f * (rbw * dby - dbw * rby + (rbz * dbx - rbx * dbz));
    float tzz = 2.0f * (rbw * dbz - dbw * rbz + (rbx * dby - rby * dbx));

    float cx = rby * ez - rbz * ey + rbw * ex;
    float cy = rbz * ex - rbx * ez + rbw * ey;
    float cz = rbx * ey - rby * ex + rbw * ez;
    float ox = ex + 2.0f * (rby * cz - rbz * cy) + txx;
    float oy = ey + 2.0f * (rbz * cx - rbx * cz) + tyy;
    float oz = ez + 2.0f * (rbx * cy - rby * cx) + tzz;

    size_t o = ((size_t)b * V + v) * 3;
    out[o + 0] = ox; out[o + 1] = oy; out[o + 2] = oz;
    pk[b * 2 + 0] = bf16bits(ox) | (bf16bits(oy) << 16);
    pk[b * 2 + 1] = bf16bits(oz);
    if (mode == 2) {
      out[LAPOFF + o + 0] = 0.f;
      out[LAPOFF + o + 1] = 0.f;
      out[LAPOFF + o + 2] = 0.f;
    }
  }

  if (mode == 0) {
    uint4* dst = reinterpret_cast<uint4*>(pvm16 + (size_t)v * 16);
    dst[0] = make_uint4(pk[0], pk[1], pk[2], pk[3]);
    dst[1] = make_uint4(pk[4], pk[5], pk[6], pk[7]);
    dst[2] = make_uint4(pk[8], pk[9], pk[10], pk[11]);
    dst[3] = make_uint4(pk[12], pk[13], pk[14], pk[15]);
  }
}

// ---------------------------------------------------------------------------
// 256-way edge partition (single level). Bucket = st >> 10 (1024 verts each).
// Payload packs s_local(10b) | d(18b) into one int + weight.
// ---------------------------------------------------------------------------
__global__ __launch_bounds__(256) void cnt256_kernel(const int* __restrict__ st,
                                                     int* __restrict__ bcnt) {
  __shared__ int h[NB2];
  int blk = blockIdx.x, t = threadIdx.x;
  h[t] = 0;
  __syncthreads();
  int e0 = blk * EPP;
  for (int i = e0 + t; i < e0 + EPP; i += 256) atomicAdd(&h[st[i] >> 10], 1);
  __syncthreads();
  bcnt[t * PBLK + blk] = h[t];  // bucket-major
}

// scan of bcnt[NB2*PBLK]: block g scans bucket g's 256 entries
__global__ __launch_bounds__(256) void scanA_kernel(const int* __restrict__ in,
                                                    int* __restrict__ out,
                                                    int* __restrict__ bs) {
  __shared__ int s[256];
  int t = threadIdx.x;
  int i = blockIdx.x * 256 + t;
  int x = in[i];
  s[t] = x;
  __syncthreads();
  for (int off = 1; off < 256; off <<= 1) {
    int v = (t >= off) ? s[t - off] : 0;
    __syncthreads();
    s[t] += v;
    __syncthreads();
  }
  out[i] = s[t] - x;
  if (t == 255) bs[blockIdx.x] = s[t];
}

__global__ __launch_bounds__(256) void scanB_kernel(int* __restrict__ bs) {
  __shared__ int s[256];
  int t = threadIdx.x;
  int x = bs[t];
  s[t] = x;
  __syncthreads();
  for (int off = 1; off < 256; off <<= 1) {
    int v = (t >= off) ? s[t - off] : 0;
    __syncthreads();
    s[t] += v;
    __syncthreads();
  }
  bs[t] = s[t] - x;
}

__global__ __launch_bounds__(256) void scanC_kernel(int* __restrict__ out,
                                                    const int* __restrict__ bs) {
  out[blockIdx.x * 256 + threadIdx.x] += bs[blockIdx.x];
}

__global__ __launch_bounds__(256) void part256_kernel(
    const int* __restrict__ st, const int* __restrict__ ed,
    const float* __restrict__ w, const int* __restrict__ boff2,
    int2* __restrict__ ewB) {
  __shared__ int lbase[NB2];
  __shared__ int lcur[NB2];
  int blk = blockIdx.x, t = threadIdx.x;
  lbase[t] = boff2[t * PBLK + blk];
  lcur[t] = 0;
  __syncthreads();
  int e0 = blk * EPP;
  for (int i = e0 + t; i < e0 + EPP; i += 256) {
    int s = st[i];
    int b = s >> 10;
    int pos = lbase[b] + atomicAdd(&lcur[b], 1);
    ewB[pos] = make_int2(((s & 1023) << 18) | ed[i], __float_as_int(w[i]));
  }
}

// ---------------------------------------------------------------------------
// Fused gather + segment-sum: one block per 1024-vertex bucket.
// LDS acc[1024][25] f32 (stride 25 -> bank-spread). Per edge: 1 random 64 B
// pvm16 line read + 24 ds_add_f32. Coalesced lap writes at the end.
// ---------------------------------------------------------------------------
__global__ __launch_bounds__(PT5) void lap_fused_kernel(
    const int2* __restrict__ ewB, const int* __restrict__ boff2,
    const unsigned* __restrict__ pvm16, float* __restrict__ lap) {
  extern __shared__ float acc[];  // VB2 * ASTR floats = 102400 B
  int p = blockIdx.x, t = threadIdx.x;
  for (int i = t; i < VB2 * ASTR; i += PT5) acc[i] = 0.f;
  int beg = boff2[p * PBLK];
  int end = (p < NB2 - 1) ? boff2[(p + 1) * PBLK] : E;
  __syncthreads();

  for (int i = beg + t; i < end; i += PT5) {
    int2 ew = ewB[i];
    float w = __int_as_float(ew.y);
    int d = ew.x & 0x3ffff;
    int sl = ((unsigned)ew.x) >> 18;
    const uint4* q = reinterpret_cast<const uint4*>(pvm16 + (size_t)d * 16);
    uint4 q0 = q[0], q1 = q[1], q2 = q[2], q3 = q[3];
    unsigned u[16] = {q0.x, q0.y, q0.z, q0.w, q1.x, q1.y, q1.z, q1.w,
                      q2.x, q2.y, q2.z, q2.w, q3.x, q3.y, q3.z, q3.w};
    float* ac = &acc[sl * ASTR];
#pragma unroll
    for (int b = 0; b < B; ++b) {
      atomicAdd(&ac[b * 3 + 0], w * __uint_as_float(u[2 * b] << 16));
      atomicAdd(&ac[b * 3 + 1], w * __uint_as_float(u[2 * b] & 0xffff0000u));
      atomicAdd(&ac[b * 3 + 2], w * __uint_as_float(u[2 * b + 1] << 16));
    }
  }
  __syncthreads();

  int v0 = p * VB2;
  for (int i = t; i < VB2; i += PT5) {
#pragma unroll
    for (int b = 0; b < B; ++b) {
      size_t o = ((size_t)b * V + v0 + i) * 3;
      lap[o + 0] = acc[i * ASTR + b * 3 + 0];
      lap[o + 1] = acc[i * ASTR + b * 3 + 1];
      lap[o + 2] = acc[i * ASTR + b * 3 + 2];
    }
  }
}

// Tier-C fallback: per-edge atomic scatter.
__global__ __launch_bounds__(256) void lap_atomic_kernel(
    const float* __restrict__ lapw, const int* __restrict__ st,
    const int* __restrict__ ed, const float* __restrict__ posed,
    float* __restrict__ lap) {
  int e = blockIdx.x * blockDim.x + threadIdx.x;
  if (e >= E) return;
  float w = lapw[e];
  int s = st[e];
  int d = ed[e];
#pragma unroll
  for (int b = 0; b < B; ++b) {
    size_t pb = ((size_t)b * V + d) * 3;
    size_t ob = ((size_t)b * V + s) * 3;
    atomicAdd(&lap[ob + 0], w * posed[pb + 0]);
    atomicAdd(&lap[ob + 1], w * posed[pb + 1]);
    atomicAdd(&lap[ob + 2], w * posed[pb + 2]);
  }
}

extern "C" void kernel_launch(void* const* d_in, const int* in_sizes, int n_in,
                              void* d_out, int out_size, void* d_ws, size_t ws_size,
                              hipStream_t stream) {
  const float* tv    = (const float*)d_in[0];
  const float* jquat = (const float*)d_in[1];
  const float* jtran = (const float*)d_in[2];
  const float* sw    = (const float*)d_in[3];
  const float* npos  = (const float*)d_in[4];
  const float* nquat = (const float*)d_in[5];
  const float* ntran = (const float*)d_in[6];
  const float* lw    = (const float*)d_in[7];
  const float* lapw  = (const float*)d_in[8];
  const int*   sidx  = (const int*)d_in[9];
  const int*   lidx  = (const int*)d_in[10];
  const int*   lst   = (const int*)d_in[11];
  const int*   led   = (const int*)d_in[12];
  float* out = (float*)d_out;
  float* lap = out + (size_t)B * V * 3;

  // ---- workspace layout (all offsets 16 B aligned) ----
  float*    jqd   = (float*)d_ws;                       // 4096 f (16 KB)
  float*    nmt   = jqd + 4096;                         // 196608 f (786 KB)
  int*      bcnt  = (int*)(nmt + 196608);               // 65536 i (256 KB)
  int*      boff2 = bcnt + NB2 * PBLK;                  // 65536 i (256 KB)
  int*      bsum  = boff2 + NB2 * PBLK;                 // 256 i (+pad to 16B)
  int2*     ewB   = (int2*)(bsum + 256 + 60);           // E int2 (14.68 MB)
  unsigned* pvm16 = (unsigned*)(ewB + E);               // V*16 u32 (16.78 MB)
  size_t need = (size_t)((char*)(pvm16 + (size_t)V * 16) - (char*)d_ws);
  int tier = (ws_size >= need) ? 0 : 2;

  jqd_kernel<<<(B * J + 255) / 256, 256, 0, stream>>>(jquat, jtran, jqd);
  nmat_kernel<<<(B * G + 255) / 256, 256, 0, stream>>>(npos, nquat, ntran, nmt);

  if (tier == 0) {
    cnt256_kernel<<<PBLK, 256, 0, stream>>>(lst, bcnt);
    scanA_kernel<<<NB2, 256, 0, stream>>>(bcnt, boff2, bsum);
    scanB_kernel<<<1, 256, 0, stream>>>(bsum);
    scanC_kernel<<<NB2, 256, 0, stream>>>(boff2, bsum);
    part256_kernel<<<PBLK, 256, 0, stream>>>(lst, led, lapw, boff2, ewB);
    posed5_kernel<<<V / PT5, PT5, G * 3 * sizeof(float4), stream>>>(
        tv, sw, lw, sidx, lidx, nmt, jqd, out, pvm16, 0);
    lap_fused_kernel<<<NB2, PT5, VB2 * ASTR * sizeof(float), stream>>>(
        ewB, boff2, pvm16, lap);
  } else {
    posed5_kernel<<<V / PT5, PT5, G * 3 * sizeof(float4), stream>>>(
        tv, sw, lw, sidx, lidx, nmt, jqd, out, (unsigned*)jqd /*unused*/, 2);
    lap_atomic_kernel<<<E / 256, 256, 0, stream>>>(lapw, lst, led, out, lap);
  }
}

// Round 11
// 173.393 us; speedup vs baseline: 2.0731x; 2.0163x over previous
//
#include <hip/hip_runtime.h>
#include <hip/hip_bf16.h>
#include <math.h>

// Problem constants (fixed by the reference setup)
constexpr int B = 8;
constexpr int V = 262144;
constexpr int J = 64;
constexpr int K = 4;
constexpr int G = 2048;
constexpr int L = 8;
constexpr int E = 1835008;
constexpr float EPS = 1e-8f;
constexpr int PT5 = 1024;      // posed5 block size (1 block/CU, 16 waves)
constexpr int NB2 = 256;       // fine buckets (1024 vertices each)
constexpr int VB2 = V / NB2;   // 1024
constexpr int PBLK = 256;      // partition blocks
constexpr int EPP = E / PBLK;  // 7168 edges per partition block
constexpr int CHK = 4096;      // lap_sorted chunk size (edges)

__device__ inline unsigned bf16bits(float x) {
  unsigned u = __float_as_uint(x);
  return (u + 0x7fffu + ((u >> 16) & 1u)) >> 16;  // round-to-nearest-even
}

// ---------------------------------------------------------------------------
// Kernel 0: per (b,j) normalized joint quat + dual part jd = 0.5*qmul((0,t),q)
// ---------------------------------------------------------------------------
__global__ __launch_bounds__(256) void jqd_kernel(
    const float* __restrict__ jquat, const float* __restrict__ jtrans,
    float* __restrict__ ws) {
  int i = blockIdx.x * blockDim.x + threadIdx.x;
  if (i >= B * J) return;
  float qw = jquat[i * 4 + 0];
  float qx = jquat[i * 4 + 1];
  float qy = jquat[i * 4 + 2];
  float qz = jquat[i * 4 + 3];
  float inv = 1.0f / (sqrtf(qw * qw + qx * qx + qy * qy + qz * qz) + EPS);
  qw *= inv; qx *= inv; qy *= inv; qz *= inv;
  float tx = jtrans[i * 3 + 0];
  float ty = jtrans[i * 3 + 1];
  float tz = jtrans[i * 3 + 2];
  float dw = -0.5f * (tx * qx + ty * qy + tz * qz);
  float dx = 0.5f * (qw * tx + (ty * qz - tz * qy));
  float dy = 0.5f * (qw * ty + (tz * qx - tx * qz));
  float dz = 0.5f * (qw * tz + (tx * qy - ty * qx));
  float* o = ws + (size_t)i * 8;
  o[0] = qw; o[1] = qx; o[2] = qy; o[3] = qz;
  o[4] = dw; o[5] = dx; o[6] = dy; o[7] = dz;
}

// ---------------------------------------------------------------------------
// Kernel 0b: per (b,g) affine transform, packed [G][3]float4 per batch.
// warped = M*p + T, T = gp + nt - M*gp. Row r = float4 {m_r0,m_r1,m_r2,t_r}.
// ---------------------------------------------------------------------------
__global__ __launch_bounds__(256) void nmat_kernel(
    const float* __restrict__ npos, const float* __restrict__ nquat,
    const float* __restrict__ ntrans, float* __restrict__ nmt) {
  int i = blockIdx.x * blockDim.x + threadIdx.x;
  if (i >= B * G) return;
  int g = i & (G - 1);
  float4 q = *reinterpret_cast<const float4*>(nquat + (size_t)i * 4);
  float qw = q.x, qx = q.y, qy = q.z, qz = q.w;
  float inv = 1.0f / (sqrtf(qw * qw + qx * qx + qy * qy + qz * qz) + EPS);
  qw *= inv; qx *= inv; qy *= inv; qz *= inv;
  float xx = qx * qx, yy = qy * qy, zz = qz * qz;
  float xy = qx * qy, xz = qx * qz, yz = qy * qz;
  float wx = qw * qx, wy = qw * qy, wz = qw * qz;
  float m00 = 1.f - 2.f * (yy + zz), m01 = 2.f * (xy - wz), m02 = 2.f * (xz + wy);
  float m10 = 2.f * (xy + wz), m11 = 1.f - 2.f * (xx + zz), m12 = 2.f * (yz - wx);
  float m20 = 2.f * (xz - wy), m21 = 2.f * (yz + wx), m22 = 1.f - 2.f * (xx + yy);
  float gx = npos[g * 3 + 0], gy = npos[g * 3 + 1], gz = npos[g * 3 + 2];
  float tx = ntrans[(size_t)i * 3 + 0] + gx - (m00 * gx + m01 * gy + m02 * gz);
  float ty = ntrans[(size_t)i * 3 + 1] + gy - (m10 * gx + m11 * gy + m12 * gz);
  float tz = ntrans[(size_t)i * 3 + 2] + gz - (m20 * gx + m21 * gy + m22 * gz);
  float4* o = reinterpret_cast<float4*>(nmt + (size_t)i * 12);
  o[0] = make_float4(m00, m01, m02, tx);
  o[1] = make_float4(m10, m11, m12, ty);
  o[2] = make_float4(m20, m21, m22, tz);
}

// ---------------------------------------------------------------------------
// posed5 — LDS-staged node table, ds_read_b128 gathers. 1024 thr, 96 KB LDS.
// mode: 0 = write pvm16, 2 = no pvm16 + zero lap
// ---------------------------------------------------------------------------
__global__ __launch_bounds__(PT5) void posed5_kernel(
    const float* __restrict__ tv, const float* __restrict__ sw_in,
    const float* __restrict__ lw_in, const int* __restrict__ sidx,
    const int* __restrict__ lidx, const float* __restrict__ nmt,
    const float* __restrict__ jqd, float* __restrict__ out,
    unsigned* __restrict__ pvm16, int mode) {
  extern __shared__ float4 sm4[];  // G*3 float4 = 98304 B
  int v = blockIdx.x * PT5 + threadIdx.x;

  float px = tv[(size_t)v * 3 + 0];
  float py = tv[(size_t)v * 3 + 1];
  float pz = tv[(size_t)v * 3 + 2];

  int4 si = *reinterpret_cast<const int4*>(sidx + (size_t)v * 4);
  float4 swv = *reinterpret_cast<const float4*>(sw_in + (size_t)v * 4);
  int4 li0 = *reinterpret_cast<const int4*>(lidx + (size_t)v * 8);
  int4 li1 = *reinterpret_cast<const int4*>(lidx + (size_t)v * 8 + 4);
  float4 lw0 = *reinterpret_cast<const float4*>(lw_in + (size_t)v * 8);
  float4 lw1 = *reinterpret_cast<const float4*>(lw_in + (size_t)v * 8 + 4);

  float sinv = 1.0f / (swv.x + swv.y + swv.z + swv.w + EPS);
  float swn[K] = {swv.x * sinv, swv.y * sinv, swv.z * sinv, swv.w * sinv};
  int sj[K] = {si.x, si.y, si.z, si.w};

  float linv =
      1.0f / (lw0.x + lw0.y + lw0.z + lw0.w + lw1.x + lw1.y + lw1.z + lw1.w + EPS);
  float lwn[L] = {lw0.x * linv, lw0.y * linv, lw0.z * linv, lw0.w * linv,
                  lw1.x * linv, lw1.y * linv, lw1.z * linv, lw1.w * linv};
  int gi[L] = {li0.x * 3, li0.y * 3, li0.z * 3, li0.w * 3,
               li1.x * 3, li1.y * 3, li1.z * 3, li1.w * 3};

  constexpr size_t LAPOFF = (size_t)B * V * 3;
  unsigned pk[2 * B];

  for (int b = 0; b < B; ++b) {
    __syncthreads();
    const float4* src = reinterpret_cast<const float4*>(nmt + (size_t)b * G * 12);
#pragma unroll
    for (int it = 0; it < (G * 3) / PT5; ++it) {
      int q = it * PT5 + threadIdx.x;
      sm4[q] = src[q];
    }
    __syncthreads();

    float ex = 0.f, ey = 0.f, ez = 0.f;
#pragma unroll
    for (int l = 0; l < L; ++l) {
      float4 r0 = sm4[gi[l] + 0];
      float4 r1 = sm4[gi[l] + 1];
      float4 r2 = sm4[gi[l] + 2];
      float w = lwn[l];
      ex += w * (r0.x * px + r0.y * py + r0.z * pz + r0.w);
      ey += w * (r1.x * px + r1.y * py + r1.z * pz + r1.w);
      ez += w * (r2.x * px + r2.y * py + r2.z * pz + r2.w);
    }

    float rbw = 0.f, rbx = 0.f, rby = 0.f, rbz = 0.f;
    float dbw = 0.f, dbx = 0.f, dby = 0.f, dbz = 0.f;
    float r0w = 0.f, r0x = 0.f, r0y = 0.f, r0z = 0.f;
#pragma unroll
    for (int k = 0; k < K; ++k) {
      const float* eptr = jqd + ((size_t)b * J + sj[k]) * 8;
      float4 qf = *reinterpret_cast<const float4*>(eptr);
      float4 df = *reinterpret_cast<const float4*>(eptr + 4);
      float qw = qf.x, qx = qf.y, qy = qf.z, qz = qf.w;
      if (k == 0) { r0w = qw; r0x = qx; r0y = qy; r0z = qz; }
      float dotr = qw * r0w + qx * r0x + qy * r0y + qz * r0z;
      float s = (dotr >= 0.0f) ? swn[k] : -swn[k];
      rbw += s * qw; rbx += s * qx; rby += s * qy; rbz += s * qz;
      dbw += s * df.x; dbx += s * df.y; dby += s * df.z; dbz += s * df.w;
    }
    float ninv = 1.0f / (sqrtf(rbw * rbw + rbx * rbx + rby * rby + rbz * rbz) + EPS);
    rbw *= ninv; rbx *= ninv; rby *= ninv; rbz *= ninv;
    dbw *= ninv; dbx *= ninv; dby *= ninv; dbz *= ninv;

    float txx = 2.0f * (rbw * dbx - dbw * rbx + (rby * dbz - rbz * dby));
    float tyy = 2.0f * (rbw * dby - dbw * rby + (rbz * dbx - rbx * dbz));
    float tzz = 2.0f * (rbw * dbz - dbw * rbz + (rbx * dby - rby * dbx));

    float cx = rby * ez - rbz * ey + rbw * ex;
    float cy = rbz * ex - rbx * ez + rbw * ey;
    float cz = rbx * ey - rby * ex + rbw * ez;
    float ox = ex + 2.0f * (rby * cz - rbz * cy) + txx;
    float oy = ey + 2.0f * (rbz * cx - rbx * cz) + tyy;
    float oz = ez + 2.0f * (rbx * cy - rby * cx) + tzz;

    size_t o = ((size_t)b * V + v) * 3;
    out[o + 0] = ox; out[o + 1] = oy; out[o + 2] = oz;
    pk[b * 2 + 0] = bf16bits(ox) | (bf16bits(oy) << 16);
    pk[b * 2 + 1] = bf16bits(oz);
    if (mode == 2) {
      out[LAPOFF + o + 0] = 0.f;
      out[LAPOFF + o + 1] = 0.f;
      out[LAPOFF + o + 2] = 0.f;
    }
  }

  if (mode == 0) {
    uint4* dst = reinterpret_cast<uint4*>(pvm16 + (size_t)v * 16);
    dst[0] = make_uint4(pk[0], pk[1], pk[2], pk[3]);
    dst[1] = make_uint4(pk[4], pk[5], pk[6], pk[7]);
    dst[2] = make_uint4(pk[8], pk[9], pk[10], pk[11]);
    dst[3] = make_uint4(pk[12], pk[13], pk[14], pk[15]);
  }
}

// ---------------------------------------------------------------------------
// 256-way edge partition (single level). Bucket = st >> 10 (1024 verts each).
// Payload packs s_local(10b) | d(18b) into one int + weight.
// ---------------------------------------------------------------------------
__global__ __launch_bounds__(256) void cnt256_kernel(const int* __restrict__ st,
                                                     int* __restrict__ bcnt) {
  __shared__ int h[NB2];
  int blk = blockIdx.x, t = threadIdx.x;
  h[t] = 0;
  __syncthreads();
  int e0 = blk * EPP;
  for (int i = e0 + t; i < e0 + EPP; i += 256) atomicAdd(&h[st[i] >> 10], 1);
  __syncthreads();
  bcnt[t * PBLK + blk] = h[t];  // bucket-major
}

// scan of bcnt[NB2*PBLK]: block g scans bucket g's 256 entries
__global__ __launch_bounds__(256) void scanA_kernel(const int* __restrict__ in,
                                                    int* __restrict__ out,
                                                    int* __restrict__ bs) {
  __shared__ int s[256];
  int t = threadIdx.x;
  int i = blockIdx.x * 256 + t;
  int x = in[i];
  s[t] = x;
  __syncthreads();
  for (int off = 1; off < 256; off <<= 1) {
    int v = (t >= off) ? s[t - off] : 0;
    __syncthreads();
    s[t] += v;
    __syncthreads();
  }
  out[i] = s[t] - x;
  if (t == 255) bs[blockIdx.x] = s[t];
}

__global__ __launch_bounds__(256) void scanB_kernel(int* __restrict__ bs) {
  __shared__ int s[256];
  int t = threadIdx.x;
  int x = bs[t];
  s[t] = x;
  __syncthreads();
  for (int off = 1; off < 256; off <<= 1) {
    int v = (t >= off) ? s[t - off] : 0;
    __syncthreads();
    s[t] += v;
    __syncthreads();
  }
  bs[t] = s[t] - x;
}

__global__ __launch_bounds__(256) void scanC_kernel(int* __restrict__ out,
                                                    const int* __restrict__ bs) {
  out[blockIdx.x * 256 + threadIdx.x] += bs[blockIdx.x];
}

__global__ __launch_bounds__(256) void part256_kernel(
    const int* __restrict__ st, const int* __restrict__ ed,
    const float* __restrict__ w, const int* __restrict__ boff2,
    int2* __restrict__ ewB) {
  __shared__ int lbase[NB2];
  __shared__ int lcur[NB2];
  int blk = blockIdx.x, t = threadIdx.x;
  lbase[t] = boff2[t * PBLK + blk];
  lcur[t] = 0;
  __syncthreads();
  int e0 = blk * EPP;
  for (int i = e0 + t; i < e0 + EPP; i += 256) {
    int s = st[i];
    int b = s >> 10;
    int pos = lbase[b] + atomicAdd(&lcur[b], 1);
    ewB[pos] = make_int2(((s & 1023) << 18) | ed[i], __float_as_int(w[i]));
  }
}

// ---------------------------------------------------------------------------
// lap_sorted: one 1024-thread block per 1024-vertex bucket. Per 4096-edge
// chunk: LDS counting sort by s_local, then thread t (= vertex t) walks its
// row, random-reads pvm16 (1×64 B line/edge), accumulates in registers.
// No output atomics; coalesced lap write at the end.
// ---------------------------------------------------------------------------
__global__ __launch_bounds__(1024) void lap_sorted_kernel(
    const int2* __restrict__ ewB, const int* __restrict__ boff2,
    const unsigned* __restrict__ pvm16, float* __restrict__ lap) {
  __shared__ int2 eL[CHK];     // 32 KB sorted chunk
  __shared__ int rs[VB2];      // hist -> inclusive -> exclusive rowstart
  __shared__ int cur[VB2];     // scatter cursors
  int p = blockIdx.x, t = threadIdx.x;
  int beg = boff2[p * PBLK];
  int end = (p < NB2 - 1) ? boff2[(p + 1) * PBLK] : E;

  float acc[24];
#pragma unroll
  for (int i = 0; i < 24; ++i) acc[i] = 0.f;

  for (int cbeg = beg; cbeg < end; cbeg += CHK) {
    int cnt = min(CHK, end - cbeg);
    rs[t] = 0;
    __syncthreads();

    // load chunk edges to registers + histogram s_local
    int2 er[CHK / 1024];
#pragma unroll
    for (int j = 0; j < CHK / 1024; ++j) {
      int idx = j * 1024 + t;
      if (idx < cnt) {
        er[j] = ewB[cbeg + idx];
        atomicAdd(&rs[((unsigned)er[j].x) >> 18], 1);
      }
    }
    __syncthreads();

    // Hillis-Steele inclusive scan over rs[1024]
    int x = rs[t];
    for (int off = 1; off < VB2; off <<= 1) {
      int v = (t >= off) ? rs[t - off] : 0;
      __syncthreads();
      rs[t] += v;
      __syncthreads();
    }
    int excl = rs[t] - x;
    __syncthreads();
    rs[t] = excl;
    cur[t] = excl;
    __syncthreads();

    // scatter registered edges into sorted LDS list
#pragma unroll
    for (int j = 0; j < CHK / 1024; ++j) {
      int idx = j * 1024 + t;
      if (idx < cnt) {
        int sl = ((unsigned)er[j].x) >> 18;
        int pos = atomicAdd(&cur[sl], 1);
        eL[pos] = er[j];
      }
    }
    __syncthreads();

    // thread t = vertex t: walk own row, random pvm16 read, reg accumulate
    int rbeg = rs[t];
    int rend = (t < VB2 - 1) ? rs[t + 1] : cnt;
    for (int j = rbeg; j < rend; ++j) {
      int2 ew = eL[j];
      float w = __int_as_float(ew.y);
      int d = ew.x & 0x3ffff;
      const uint4* q = reinterpret_cast<const uint4*>(pvm16 + (size_t)d * 16);
      uint4 q0 = q[0], q1 = q[1], q2 = q[2], q3 = q[3];
      unsigned u[16] = {q0.x, q0.y, q0.z, q0.w, q1.x, q1.y, q1.z, q1.w,
                        q2.x, q2.y, q2.z, q2.w, q3.x, q3.y, q3.z, q3.w};
#pragma unroll
      for (int b = 0; b < B; ++b) {
        acc[b * 3 + 0] += w * __uint_as_float(u[2 * b] << 16);
        acc[b * 3 + 1] += w * __uint_as_float(u[2 * b] & 0xffff0000u);
        acc[b * 3 + 2] += w * __uint_as_float(u[2 * b + 1] << 16);
      }
    }
    __syncthreads();  // eL/rs reused next chunk
  }

  int v = p * VB2 + t;
#pragma unroll
  for (int b = 0; b < B; ++b) {
    size_t o = ((size_t)b * V + v) * 3;
    lap[o + 0] = acc[b * 3 + 0];
    lap[o + 1] = acc[b * 3 + 1];
    lap[o + 2] = acc[b * 3 + 2];
  }
}

// Tier-C fallback: per-edge atomic scatter.
__global__ __launch_bounds__(256) void lap_atomic_kernel(
    const float* __restrict__ lapw, const int* __restrict__ st,
    const int* __restrict__ ed, const float* __restrict__ posed,
    float* __restrict__ lap) {
  int e = blockIdx.x * blockDim.x + threadIdx.x;
  if (e >= E) return;
  float w = lapw[e];
  int s = st[e];
  int d = ed[e];
#pragma unroll
  for (int b = 0; b < B; ++b) {
    size_t pb = ((size_t)b * V + d) * 3;
    size_t ob = ((size_t)b * V + s) * 3;
    atomicAdd(&lap[ob + 0], w * posed[pb + 0]);
    atomicAdd(&lap[ob + 1], w * posed[pb + 1]);
    atomicAdd(&lap[ob + 2], w * posed[pb + 2]);
  }
}

extern "C" void kernel_launch(void* const* d_in, const int* in_sizes, int n_in,
                              void* d_out, int out_size, void* d_ws, size_t ws_size,
                              hipStream_t stream) {
  const float* tv    = (const float*)d_in[0];
  const float* jquat = (const float*)d_in[1];
  const float* jtran = (const float*)d_in[2];
  const float* sw    = (const float*)d_in[3];
  const float* npos  = (const float*)d_in[4];
  const float* nquat = (const float*)d_in[5];
  const float* ntran = (const float*)d_in[6];
  const float* lw    = (const float*)d_in[7];
  const float* lapw  = (const float*)d_in[8];
  const int*   sidx  = (const int*)d_in[9];
  const int*   lidx  = (const int*)d_in[10];
  const int*   lst   = (const int*)d_in[11];
  const int*   led   = (const int*)d_in[12];
  float* out = (float*)d_out;
  float* lap = out + (size_t)B * V * 3;

  // ---- workspace layout (all offsets 16 B aligned) ----
  float*    jqd   = (float*)d_ws;                       // 4096 f (16 KB)
  float*    nmt   = jqd + 4096;                         // 196608 f (786 KB)
  int*      bcnt  = (int*)(nmt + 196608);               // 65536 i (256 KB)
  int*      boff2 = bcnt + NB2 * PBLK;                  // 65536 i (256 KB)
  int*      bsum  = boff2 + NB2 * PBLK;                 // 256 i (+pad to 16B)
  int2*     ewB   = (int2*)(bsum + 256 + 60);           // E int2 (14.68 MB)
  unsigned* pvm16 = (unsigned*)(ewB + E);               // V*16 u32 (16.78 MB)
  size_t need = (size_t)((char*)(pvm16 + (size_t)V * 16) - (char*)d_ws);
  int tier = (ws_size >= need) ? 0 : 2;

  jqd_kernel<<<(B * J + 255) / 256, 256, 0, stream>>>(jquat, jtran, jqd);
  nmat_kernel<<<(B * G + 255) / 256, 256, 0, stream>>>(npos, nquat, ntran, nmt);

  if (tier == 0) {
    cnt256_kernel<<<PBLK, 256, 0, stream>>>(lst, bcnt);
    scanA_kernel<<<NB2, 256, 0, stream>>>(bcnt, boff2, bsum);
    scanB_kernel<<<1, 256, 0, stream>>>(bsum);
    scanC_kernel<<<NB2, 256, 0, stream>>>(boff2, bsum);
    part256_kernel<<<PBLK, 256, 0, stream>>>(lst, led, lapw, boff2, ewB);
    posed5_kernel<<<V / PT5, PT5, G * 3 * sizeof(float4), stream>>>(
        tv, sw, lw, sidx, lidx, nmt, jqd, out, pvm16, 0);
    lap_sorted_kernel<<<NB2, 1024, 0, stream>>>(ewB, boff2, pvm16, lap);
  } else {
    posed5_kernel<<<V / PT5, PT5, G * 3 * sizeof(float4), stream>>>(
        tv, sw, lw, sidx, lidx, nmt, jqd, out, (unsigned*)jqd /*unused*/, 2);
    lap_atomic_kernel<<<E / 256, 256, 0, stream>>>(lapw, lst, led, out, lap);
  }
}